// Round 10
// baseline (78.017 us; speedup 1.0000x reference)
//
#include <hip/hip_runtime.h>
#include <hip/hip_bf16.h>

#define BATCH 32
#define WW 900
#define CCH 256
#define KHALF 128     // K columns per block (K-split x2)
#define MSTRIP 128    // M rows per block
#define NCHUNK 32     // B rows staged per chunk
#define NCHUNKS 29    // 29*32 = 928 >= 900

typedef __bf16 bf16x8 __attribute__((ext_vector_type(8)));
typedef __bf16 bf16x4 __attribute__((ext_vector_type(4)));
typedef float f32x4 __attribute__((ext_vector_type(4)));

// ws layout (floats): sums[2*32*segs*256] at offset 0
// ---------------- norm pass 1: partial sums of squares ----------------
__global__ void nc_norm_partial(const float* __restrict__ x1,
                                const float* __restrict__ x2,
                                float* __restrict__ sums,
                                int segs, int rowsper) {
    int blk = blockIdx.x;
    int seg = blk % segs;
    int b = (blk / segs) & 31;
    int which = blk / (segs * 32);
    const float* x = which ? x2 : x1;
    int c = threadIdx.x;
    int r0 = seg * rowsper;
    int r1 = r0 + rowsper;
    if (r1 > WW) r1 = WW;
    const float* p = x + ((size_t)b * WW + r0) * CCH + c;
    float s = 0.f;
    #pragma unroll 4
    for (int w = 0; w < r1 - r0; ++w) {
        float v = p[(size_t)w * CCH];
        s = fmaf(v, v, s);
    }
    sums[(((size_t)(which * 32 + b)) * segs + seg) * CCH + c] = s;
}

// ---------------- main: R6-proven GEMM skeleton + fused finalize + raw B ----------------
// grid = 512: b = blockIdx&31 (XCD-local per batch), strip = (blockIdx>>5)&7, kh = blockIdx>>8.
// A' = x1*inv1*inv2 staged once in LDS (bf16, swizzled); B = raw x2, double-buffered,
// coalesced stage, 1 barrier/chunk. Epilogue identical to the 45.9 us R6 kernel:
// bijective scatter [mu][dr] -> per-wave rowsum -> diag -> ownership fold.
template <int SEGS>
__global__ __launch_bounds__(256, 2)
void nc_corr(const float* __restrict__ x1,
             const float* __restrict__ x2,
             const float* __restrict__ sums,
             float* __restrict__ out) {
    __shared__ __bf16 Abuf[MSTRIP * KHALF];       // 32 KB
    __shared__ __bf16 Bbuf[2][NCHUNK * KHALF];    // 2 x 8 KB
    __shared__ float scratch[4][16][65];          // 16.25 KB (R6-proven layout)
    __shared__ float diag[2][4][64];              // 2 KB
    __shared__ float partial[WW];                 // 3.6 KB
    __shared__ float sumhalf[2][128];             // 1 KB

    const int tid = threadIdx.x;
    const int b = blockIdx.x & 31;
    const int strip = (blockIdx.x >> 5) & 7;
    const int kh = blockIdx.x >> 8;
    const int m0 = strip * MSTRIP;
    const int k0 = kh * KHALF;

    const float* __restrict__ x1b = x1 + (size_t)b * WW * CCH + k0;
    const float* __restrict__ x2b = x2 + (size_t)b * WW * CCH + k0;

    const int lane = tid & 63;
    const int wave = tid >> 6;     // m-slice: rows m0 + wave*32 .. +31
    const int fr = lane & 15;
    const int fq = lane >> 4;
    const int sr = tid >> 5;       // staging row base 0..7
    const int sg = tid & 31;       // staging float4 col 0..31

    // ---- B staging (raw x2: normalization folded into A) ----
    float4 st[4];
    auto loadB = [&](int chunk) {
        #pragma unroll
        for (int k = 0; k < 4; ++k) {
            const int row = chunk * NCHUNK + sr + 8 * k;
            st[k] = (row < WW) ? *(const float4*)(x2b + (size_t)row * CCH + sg * 4)
                               : make_float4(0.f, 0.f, 0.f, 0.f);
        }
    };
    auto writeB = [&](int buf) {
        #pragma unroll
        for (int k = 0; k < 4; ++k) {
            const int row = sr + 8 * k;        // 0..31
            float4 f = st[k];
            bf16x4 v = { (__bf16)f.x, (__bf16)f.y, (__bf16)f.z, (__bf16)f.w };
            *(bf16x4*)(&Bbuf[buf][row * KHALF + (((sg >> 1) ^ (row & 7)) << 3) + (sg & 1) * 4]) = v;
        }
    };

    loadB(0);

    // ---- fused finalize: 256 threads, each sums SEGS values (coalesced, unrolled) ----
    {
        const int c = k0 + (tid & 127);
        const int half = tid >> 7;            // 0: x1 sums, 1: x2 sums
        const float* sp = sums + ((size_t)(half * 32 + b)) * SEGS * CCH + c;
        float t = 0.f;
        #pragma unroll
        for (int q = 0; q < SEGS; ++q) t += sp[(size_t)q * CCH];
        sumhalf[half][tid & 127] = t;
    }

    for (int i = tid; i < WW; i += 256) partial[i] = 0.f;
    for (int i = tid; i < 4 * 16 * 65; i += 256) ((float*)scratch)[i] = 0.f;

    writeB(0);
    __syncthreads();   // sumhalf + Bbuf[0] + zeros ready

    // ---- Stage A' once: x1 * rsqrt(s1)*rsqrt(s2), coalesced, bf16, swizzled ----
    {
        f32x4 s1 = *(const f32x4*)(&sumhalf[0][sg * 4]);
        f32x4 s2 = *(const f32x4*)(&sumhalf[1][sg * 4]);
        float4 iv;
        iv.x = rsqrtf(fmaxf(s1[0], 1e-12f)) * rsqrtf(fmaxf(s2[0], 1e-12f));
        iv.y = rsqrtf(fmaxf(s1[1], 1e-12f)) * rsqrtf(fmaxf(s2[1], 1e-12f));
        iv.z = rsqrtf(fmaxf(s1[2], 1e-12f)) * rsqrtf(fmaxf(s2[2], 1e-12f));
        iv.w = rsqrtf(fmaxf(s1[3], 1e-12f)) * rsqrtf(fmaxf(s2[3], 1e-12f));
        #pragma unroll
        for (int k = 0; k < 16; ++k) {
            const int row = sr + 8 * k;        // 0..127
            const int m = m0 + row;
            float4 f = make_float4(0.f, 0.f, 0.f, 0.f);
            if (m < WW) f = *(const float4*)(x1b + (size_t)m * CCH + sg * 4);
            bf16x4 v = { (__bf16)(f.x * iv.x), (__bf16)(f.y * iv.y),
                         (__bf16)(f.z * iv.z), (__bf16)(f.w * iv.w) };
            *(bf16x4*)(&Abuf[row * KHALF + (((sg >> 1) ^ (row & 7)) << 3) + (sg & 1) * 4]) = v;
        }
    }
    __syncthreads();   // Abuf ready

    // ---- main loop: byte-identical schedule to the 45.9 us R6 kernel ----
    int cur = 0;
    for (int chunk = 0; chunk < NCHUNKS; ++chunk) {
        if (chunk + 1 < NCHUNKS) loadB(chunk + 1);   // issue early (T14)

        f32x4 acc[2][2];
        #pragma unroll
        for (int mt = 0; mt < 2; ++mt)
            #pragma unroll
            for (int nt = 0; nt < 2; ++nt)
                acc[mt][nt] = (f32x4){0.f, 0.f, 0.f, 0.f};

        #pragma unroll
        for (int kk = 0; kk < 4; ++kk) {
            bf16x8 afm[2], bfr[2];
            #pragma unroll
            for (int mt = 0; mt < 2; ++mt) {
                const int row = wave * 32 + mt * 16 + fr;
                const int g = (kk * 4 + fq) ^ (row & 7);
                afm[mt] = *(const bf16x8*)(&Abuf[row * KHALF + g * 8]);
            }
            #pragma unroll
            for (int nt = 0; nt < 2; ++nt) {
                const int row = nt * 16 + fr;
                const int g = (kk * 4 + fq) ^ (row & 7);
                bfr[nt] = *(const bf16x8*)(&Bbuf[cur][row * KHALF + g * 8]);
            }
            #pragma unroll
            for (int mt = 0; mt < 2; ++mt)
                #pragma unroll
                for (int nt = 0; nt < 2; ++nt)
                    acc[mt][nt] = __builtin_amdgcn_mfma_f32_16x16x32_bf16(
                        afm[mt], bfr[nt], acc[mt][nt], 0, 0, 0);
        }

        // ---- epilogue: combine equal tile-diagonals, bijective scatter ----
        {
            f32x4 c0 = acc[0][1];                    // dd = 0
            f32x4 c1 = acc[0][0] + acc[1][1];        // dd = 1
            f32x4 c2 = acc[1][0];                    // dd = 2
            const int mub = 4 * fq;
            #pragma unroll
            for (int r = 0; r < 4; ++r) {
                const int mu = mub + r;
                const int dr = mu - fr + 15;         // 0..30
                scratch[wave][mu][dr]      = c0[r];
                scratch[wave][mu][dr + 16] = c1[r];
                scratch[wave][mu][dr + 32] = c2[r];
            }
        }
        // ---- per-wave row-sum: lane owns diagonal delta_rel = lane ----
        {
            float s = 0.f;
            #pragma unroll
            for (int m = 0; m < 16; ++m) s += scratch[wave][m][lane];
            diag[chunk & 1][wave][lane] = s;
        }

        if (chunk + 1 < NCHUNKS) writeB(cur ^ 1);
        __syncthreads();

        // ---- ownership fold: unique j per tid -> plain LDS RMW, no atomics ----
        if (tid < 159) {
            float s = 0.f;
            #pragma unroll
            for (int w = 0; w < 4; ++w) {
                const int dr = tid - 32 * w;
                if (dr >= 0 && dr < 63) s += diag[chunk & 1][w][dr];
            }
            int v = m0 - 32 * chunk + tid + 1319;    // in [423, 2373]
            if (v >= 1800) v -= 900;
            if (v >= 900) v -= 900;
            partial[v] += s;
        }
        cur ^= 1;
    }

    __syncthreads();
    for (int i = tid; i < WW; i += 256)
        unsafeAtomicAdd(&out[(size_t)b * WW + i], partial[i]);  // 16 blocks per batch
}

extern "C" void kernel_launch(void* const* d_in, const int* in_sizes, int n_in,
                              void* d_out, int out_size, void* d_ws, size_t ws_size,
                              hipStream_t stream) {
    const float* x1 = (const float*)d_in[0];
    const float* x2 = (const float*)d_in[1];
    float* out = (float*)d_out;
    float* ws = (float*)d_ws;

    const size_t need15 = (size_t)2 * 32 * 15 * 256 * sizeof(float);  // 983 KB
    const int segs = (ws_size >= need15) ? 15 : 4;
    const int rowsper = (WW + segs - 1) / segs;

    hipMemsetAsync(d_out, 0, (size_t)out_size * sizeof(float), stream);
    nc_norm_partial<<<2 * 32 * segs, 256, 0, stream>>>(x1, x2, ws, segs, rowsper);
    if (segs == 15) nc_corr<15><<<512, 256, 0, stream>>>(x1, x2, ws, out);
    else            nc_corr<4><<<512, 256, 0, stream>>>(x1, x2, ws, out);
}

// Round 11
// 58.067 us; speedup vs baseline: 1.3436x; 1.3436x over previous
//
#include <hip/hip_runtime.h>
#include <hip/hip_bf16.h>

#define BATCH 32
#define WW 900
#define CCH 256
#define PVAL 450
#define KHALF 128     // K columns per block (K-split x2)
#define MSTRIP 128    // M rows per block
#define NCHUNK 32     // B rows staged per chunk
#define NCHUNKS 29    // 29*32 = 928 >= 900

typedef __bf16 bf16x8 __attribute__((ext_vector_type(8)));
typedef __bf16 bf16x4 __attribute__((ext_vector_type(4)));
typedef float f32x4 __attribute__((ext_vector_type(4)));

// ws layout (floats): sums [0, 64*segs*256); inv [INV15_OFF or INV4_OFF, +16384)
#define INV15_OFF 245760   // after 64*15*256 sums
#define INV4_OFF  65536    // after 64*4*256 sums (small-ws fallback, = R6 layout)

// ---------------- norm pass 1: partial sums of squares (+ fused out-zeroing) ----------------
__global__ void nc_norm_partial(const float* __restrict__ x1,
                                const float* __restrict__ x2,
                                float* __restrict__ sums,
                                float* __restrict__ out, int out_n,
                                int segs, int rowsper) {
    int blk = blockIdx.x;
    int oz = blk * 256 + threadIdx.x;
    if (oz < out_n) out[oz] = 0.f;          // replaces the hipMemsetAsync dispatch
    int seg = blk % segs;
    int b = (blk / segs) & 31;
    int which = blk / (segs * 32);
    const float* x = which ? x2 : x1;
    int c = threadIdx.x;
    int r0 = seg * rowsper;
    int r1 = r0 + rowsper;
    if (r1 > WW) r1 = WW;
    const float* p = x + ((size_t)b * WW + r0) * CCH + c;
    float s = 0.f;
    #pragma unroll 4
    for (int w = 0; w < r1 - r0; ++w) {
        float v = p[(size_t)w * CCH];
        s = fmaf(v, v, s);
    }
    sums[(((size_t)(which * 32 + b)) * segs + seg) * CCH + c] = s;
}

// ---------------- norm pass 2: inv = rsqrt(max(sum, eps)) ----------------
template <int SEGS>
__global__ void nc_norm_finalize(float* __restrict__ ws, float* __restrict__ inv) {
    int i = blockIdx.x * 256 + threadIdx.x;   // [0, 64*256)
    int c = i & 255;
    int wb = i >> 8;                          // which*32 + b
    const float* s = ws + (size_t)wb * SEGS * CCH + c;
    float t = 0.f;
    #pragma unroll
    for (int q = 0; q < SEGS; ++q) t += s[(size_t)q * CCH];
    inv[i] = rsqrtf(fmaxf(t, 1e-12f));
}

// ---------------- main: GEMM + atomic-free diagonal reduction ----------------
// VERBATIM the 45.9 us round-6-measured kernel; only change: inv arrives as its own
// pointer arg (was ws + 65536) so the norm layout can vary without touching this body.
__global__ __launch_bounds__(256, 2)
void nc_corr(const float* __restrict__ x1,
             const float* __restrict__ x2,
             const float* __restrict__ invp,
             float* __restrict__ out) {
    __shared__ __bf16 Abuf[MSTRIP * KHALF];       // 32 KB
    __shared__ __bf16 Bbuf[2][NCHUNK * KHALF];    // 2 x 8 KB
    __shared__ float scratch[4][16][65];          // 16.25 KB  (bank = (mu+dr)&31 -> 2-way, free)
    __shared__ float diag[2][4][64];              // 2 KB (double-buffered: no extra barrier)
    __shared__ float partial[WW];                 // 3.6 KB

    const int tid = threadIdx.x;
    const int b = blockIdx.x & 31;
    const int strip = (blockIdx.x >> 5) & 7;
    const int kh = blockIdx.x >> 8;
    const int m0 = strip * MSTRIP;
    const int k0 = kh * KHALF;

    const float* __restrict__ inv1 = invp + b * CCH + k0;
    const float* __restrict__ inv2 = invp + (BATCH + b) * CCH + k0;
    const float* __restrict__ x1b = x1 + (size_t)b * WW * CCH + k0;
    const float* __restrict__ x2b = x2 + (size_t)b * WW * CCH + k0;

    for (int i = tid; i < WW; i += 256) partial[i] = 0.f;
    for (int i = tid; i < 4 * 16 * 65; i += 256) ((float*)scratch)[i] = 0.f;

    const int lane = tid & 63;
    const int wave = tid >> 6;     // m-slice: rows m0 + wave*32 .. +31
    const int fr = lane & 15;
    const int fq = lane >> 4;

    // coalesced staging coords: thread = (sr, sg): row base sr, float4 col sg*4
    const int sr = tid >> 5;       // 0..7
    const int sg = tid & 31;       // 0..31  (32 x float4 = full 128-col row)

    // ---- Stage A once: 128 rows x 128 cols, coalesced, normalized, swizzled ----
    {
        float4 iv1 = *(const float4*)(inv1 + sg * 4);
        #pragma unroll
        for (int k = 0; k < 16; ++k) {
            const int row = sr + 8 * k;        // 0..127
            const int m = m0 + row;
            float4 f = make_float4(0.f, 0.f, 0.f, 0.f);
            if (m < WW) f = *(const float4*)(x1b + (size_t)m * CCH + sg * 4);
            bf16x4 v = { (__bf16)(f.x * iv1.x), (__bf16)(f.y * iv1.y),
                         (__bf16)(f.z * iv1.z), (__bf16)(f.w * iv1.w) };
            *(bf16x4*)(&Abuf[row * KHALF + (((sg >> 1) ^ (row & 7)) << 3) + (sg & 1) * 4]) = v;
        }
    }

    // ---- B staging: coalesced, 4 float4 per thread per chunk ----
    const float4 ivB = *(const float4*)(inv2 + sg * 4);
    float4 st[4];

    auto loadB = [&](int chunk) {
        #pragma unroll
        for (int k = 0; k < 4; ++k) {
            const int row = chunk * NCHUNK + sr + 8 * k;
            st[k] = (row < WW) ? *(const float4*)(x2b + (size_t)row * CCH + sg * 4)
                               : make_float4(0.f, 0.f, 0.f, 0.f);
        }
    };
    auto writeB = [&](int buf) {
        #pragma unroll
        for (int k = 0; k < 4; ++k) {
            const int row = sr + 8 * k;        // 0..31
            float4 f = st[k];
            bf16x4 v = { (__bf16)(f.x * ivB.x), (__bf16)(f.y * ivB.y),
                         (__bf16)(f.z * ivB.z), (__bf16)(f.w * ivB.w) };
            *(bf16x4*)(&Bbuf[buf][row * KHALF + (((sg >> 1) ^ (row & 7)) << 3) + (sg & 1) * 4]) = v;
        }
    };

    loadB(0);
    writeB(0);
    __syncthreads();   // A staged, B chunk0 staged, partial+scratch zeroed

    int cur = 0;
    for (int chunk = 0; chunk < NCHUNKS; ++chunk) {
        if (chunk + 1 < NCHUNKS) loadB(chunk + 1);   // issue early (T14)

        f32x4 acc[2][2];
        #pragma unroll
        for (int mt = 0; mt < 2; ++mt)
            #pragma unroll
            for (int nt = 0; nt < 2; ++nt)
                acc[mt][nt] = (f32x4){0.f, 0.f, 0.f, 0.f};

        #pragma unroll
        for (int kk = 0; kk < 4; ++kk) {
            bf16x8 afm[2], bfr[2];
            #pragma unroll
            for (int mt = 0; mt < 2; ++mt) {
                const int row = wave * 32 + mt * 16 + fr;
                const int g = (kk * 4 + fq) ^ (row & 7);
                afm[mt] = *(const bf16x8*)(&Abuf[row * KHALF + g * 8]);
            }
            #pragma unroll
            for (int nt = 0; nt < 2; ++nt) {
                const int row = nt * 16 + fr;
                const int g = (kk * 4 + fq) ^ (row & 7);
                bfr[nt] = *(const bf16x8*)(&Bbuf[cur][row * KHALF + g * 8]);
            }
            #pragma unroll
            for (int mt = 0; mt < 2; ++mt)
                #pragma unroll
                for (int nt = 0; nt < 2; ++nt)
                    acc[mt][nt] = __builtin_amdgcn_mfma_f32_16x16x32_bf16(
                        afm[mt], bfr[nt], acc[mt][nt], 0, 0, 0);
        }

        // ---- epilogue: combine equal tile-diagonals, bijective scatter ----
        // slot (dd, r): value for delta_rel = 16*dd + (4fq + r) - fr + 15, mu = 4fq + r.
        // (delta_rel, mu) <-> (dd, fq, fr, r) is a bijection -> plain writes, no collisions.
        {
            f32x4 c0 = acc[0][1];                    // dd = 0  (mt - nt = -1)
            f32x4 c1 = acc[0][0] + acc[1][1];        // dd = 1
            f32x4 c2 = acc[1][0];                    // dd = 2
            const int mub = 4 * fq;
            #pragma unroll
            for (int r = 0; r < 4; ++r) {
                const int mu = mub + r;
                const int dr = mu - fr + 15;         // 0..30
                scratch[wave][mu][dr]      = c0[r];
                scratch[wave][mu][dr + 16] = c1[r];
                scratch[wave][mu][dr + 32] = c2[r];
            }
        }

        // ---- per-wave row-sum: lane owns diagonal delta_rel = lane ----
        {
            float s = 0.f;
            #pragma unroll
            for (int m = 0; m < 16; ++m) s += scratch[wave][m][lane];
            diag[chunk & 1][wave][lane] = s;
        }

        if (chunk + 1 < NCHUNKS) writeB(cur ^ 1);
        __syncthreads();

        // ---- ownership fold: t = 32w + delta_rel, j unique per t -> no atomics ----
        if (tid < 159) {
            float s = 0.f;
            #pragma unroll
            for (int w = 0; w < 4; ++w) {
                const int dr = tid - 32 * w;
                if (dr >= 0 && dr < 63) s += diag[chunk & 1][w][dr];
            }
            int v = m0 - 32 * chunk + tid + 1319;    // in [423, 2373]
            if (v >= 1800) v -= 900;
            if (v >= 900) v -= 900;
            partial[v] += s;
        }
        cur ^= 1;
    }

    __syncthreads();
    for (int i = tid; i < WW; i += 256)
        unsafeAtomicAdd(&out[(size_t)b * WW + i], partial[i]);  // 16 blocks per batch
}

extern "C" void kernel_launch(void* const* d_in, const int* in_sizes, int n_in,
                              void* d_out, int out_size, void* d_ws, size_t ws_size,
                              hipStream_t stream) {
    const float* x1 = (const float*)d_in[0];
    const float* x2 = (const float*)d_in[1];
    float* out = (float*)d_out;
    float* ws = (float*)d_ws;

    const size_t need15 = (size_t)(INV15_OFF + 16384) * sizeof(float);  // ~1.05 MB
    if (ws_size >= need15) {
        const int segs = 15, rowsper = 60;
        nc_norm_partial<<<2 * 32 * segs, 256, 0, stream>>>(x1, x2, ws, out, out_size, segs, rowsper);
        nc_norm_finalize<15><<<64, 256, 0, stream>>>(ws, ws + INV15_OFF);
        nc_corr<<<512, 256, 0, stream>>>(x1, x2, ws + INV15_OFF, out);
    } else {
        const int segs = 4, rowsper = 225;
        nc_norm_partial<<<2 * 32 * segs, 256, 0, stream>>>(x1, x2, ws, out, out_size, segs, rowsper);
        nc_norm_finalize<4><<<64, 256, 0, stream>>>(ws, ws + INV4_OFF);
        nc_corr<<<512, 256, 0, stream>>>(x1, x2, ws + INV4_OFF, out);
    }
}

// Round 12
// 55.196 us; speedup vs baseline: 1.4135x; 1.0520x over previous
//
#include <hip/hip_runtime.h>
#include <hip/hip_bf16.h>

#define BATCH 32
#define WW 900
#define CCH 256
#define PVAL 450
#define KHALF 128     // K columns per block (K-split x2)
#define MSTRIP 128    // M rows per block
#define NCHUNK 32     // B rows staged per chunk
#define NCHUNKS 29    // 29*32 = 928 >= 900

typedef __bf16 bf16x8 __attribute__((ext_vector_type(8)));
typedef __bf16 bf16x4 __attribute__((ext_vector_type(4)));
typedef float f32x4 __attribute__((ext_vector_type(4)));

// ws layout (floats): sums [0, 64*segs*256); inv [INV15_OFF or INV4_OFF, +16384)
#define INV15_OFF 245760   // after 64*15*256 sums
#define INV4_OFF  65536    // after 64*4*256 sums (small-ws fallback)

// ---------------- norm pass 1: partial sums of squares (+ fused out-zeroing) ----------------
__global__ void nc_norm_partial(const float* __restrict__ x1,
                                const float* __restrict__ x2,
                                float* __restrict__ sums,
                                float* __restrict__ out, int out_n,
                                int segs, int rowsper) {
    int blk = blockIdx.x;
    int oz = blk * 256 + threadIdx.x;
    if (oz < out_n) out[oz] = 0.f;          // replaces the hipMemsetAsync dispatch
    int seg = blk % segs;
    int b = (blk / segs) & 31;
    int which = blk / (segs * 32);
    const float* x = which ? x2 : x1;
    int c = threadIdx.x;
    int r0 = seg * rowsper;
    int r1 = r0 + rowsper;
    if (r1 > WW) r1 = WW;
    const float* p = x + ((size_t)b * WW + r0) * CCH + c;
    float s = 0.f;
    #pragma unroll 4
    for (int w = 0; w < r1 - r0; ++w) {
        float v = p[(size_t)w * CCH];
        s = fmaf(v, v, s);
    }
    sums[(((size_t)(which * 32 + b)) * segs + seg) * CCH + c] = s;
}

// ---------------- norm pass 2: inv = rsqrt(max(sum, eps)) ----------------
template <int SEGS>
__global__ void nc_norm_finalize(float* __restrict__ ws, float* __restrict__ inv) {
    int i = blockIdx.x * 256 + threadIdx.x;   // [0, 64*256)
    int c = i & 255;
    int wb = i >> 8;                          // which*32 + b
    const float* s = ws + (size_t)wb * SEGS * CCH + c;
    float t = 0.f;
    #pragma unroll
    for (int q = 0; q < SEGS; ++q) t += s[(size_t)q * CCH];
    inv[i] = rsqrtf(fmaxf(t, 1e-12f));
}

// ---------------- main: GEMM + atomic-free diagonal reduction ----------------
// R11 body with exactly one coupled change: A fragments hoisted to registers
// (loaded once, pinned) + sched_barrier(0) after loadB to lock the prefetch
// position (R7's diagnosed failure mechanism was loadB sinking to writeB).
__global__ __launch_bounds__(256, 2)
void nc_corr(const float* __restrict__ x1,
             const float* __restrict__ x2,
             const float* __restrict__ invp,
             float* __restrict__ out) {
    __shared__ __bf16 Abuf[MSTRIP * KHALF];       // 32 KB
    __shared__ __bf16 Bbuf[2][NCHUNK * KHALF];    // 2 x 8 KB
    __shared__ float scratch[4][16][65];          // 16.25 KB
    __shared__ float diag[2][4][64];              // 2 KB
    __shared__ float partial[WW];                 // 3.6 KB

    const int tid = threadIdx.x;
    const int b = blockIdx.x & 31;
    const int strip = (blockIdx.x >> 5) & 7;
    const int kh = blockIdx.x >> 8;
    const int m0 = strip * MSTRIP;
    const int k0 = kh * KHALF;

    const float* __restrict__ inv1 = invp + b * CCH + k0;
    const float* __restrict__ inv2 = invp + (BATCH + b) * CCH + k0;
    const float* __restrict__ x1b = x1 + (size_t)b * WW * CCH + k0;
    const float* __restrict__ x2b = x2 + (size_t)b * WW * CCH + k0;

    for (int i = tid; i < WW; i += 256) partial[i] = 0.f;
    for (int i = tid; i < 4 * 16 * 65; i += 256) ((float*)scratch)[i] = 0.f;

    const int lane = tid & 63;
    const int wave = tid >> 6;     // m-slice: rows m0 + wave*32 .. +31
    const int fr = lane & 15;
    const int fq = lane >> 4;

    // coalesced staging coords
    const int sr = tid >> 5;       // 0..7
    const int sg = tid & 31;       // 0..31

    // ---- Stage A once: 128 rows x 128 cols, coalesced, normalized, swizzled ----
    {
        float4 iv1 = *(const float4*)(inv1 + sg * 4);
        #pragma unroll
        for (int k = 0; k < 16; ++k) {
            const int row = sr + 8 * k;        // 0..127
            const int m = m0 + row;
            float4 f = make_float4(0.f, 0.f, 0.f, 0.f);
            if (m < WW) f = *(const float4*)(x1b + (size_t)m * CCH + sg * 4);
            bf16x4 v = { (__bf16)(f.x * iv1.x), (__bf16)(f.y * iv1.y),
                         (__bf16)(f.z * iv1.z), (__bf16)(f.w * iv1.w) };
            *(bf16x4*)(&Abuf[row * KHALF + (((sg >> 1) ^ (row & 7)) << 3) + (sg & 1) * 4]) = v;
        }
    }

    // ---- B staging: coalesced, 4 float4 per thread per chunk ----
    const float4 ivB = *(const float4*)(inv2 + sg * 4);
    float4 st[4];

    auto loadB = [&](int chunk) {
        #pragma unroll
        for (int k = 0; k < 4; ++k) {
            const int row = chunk * NCHUNK + sr + 8 * k;
            st[k] = (row < WW) ? *(const float4*)(x2b + (size_t)row * CCH + sg * 4)
                               : make_float4(0.f, 0.f, 0.f, 0.f);
        }
    };
    auto writeB = [&](int buf) {
        #pragma unroll
        for (int k = 0; k < 4; ++k) {
            const int row = sr + 8 * k;        // 0..31
            float4 f = st[k];
            bf16x4 v = { (__bf16)(f.x * ivB.x), (__bf16)(f.y * ivB.y),
                         (__bf16)(f.z * ivB.z), (__bf16)(f.w * ivB.w) };
            *(bf16x4*)(&Bbuf[buf][row * KHALF + (((sg >> 1) ^ (row & 7)) << 3) + (sg & 1) * 4]) = v;
        }
    };

    loadB(0);
    writeB(0);
    __syncthreads();   // A staged, B chunk0 staged, partial+scratch zeroed

    // ---- A fragments: LDS -> registers ONCE (32 VGPR), pinned against re-sink ----
    bf16x8 afm[2][4];
    #pragma unroll
    for (int mt = 0; mt < 2; ++mt)
        #pragma unroll
        for (int kk = 0; kk < 4; ++kk) {
            const int row = wave * 32 + mt * 16 + fr;
            const int g = (kk * 4 + fq) ^ (row & 7);
            afm[mt][kk] = *(const bf16x8*)(&Abuf[row * KHALF + g * 8]);
        }
    #pragma unroll
    for (int mt = 0; mt < 2; ++mt)
        #pragma unroll
        for (int kk = 0; kk < 4; ++kk)
            asm volatile("" : "+v"(afm[mt][kk]));

    int cur = 0;
    for (int chunk = 0; chunk < NCHUNKS; ++chunk) {
        if (chunk + 1 < NCHUNKS) {
            loadB(chunk + 1);                        // issue early (T14)
            __builtin_amdgcn_sched_barrier(0);       // lock prefetch position (anti-sink)
        }

        f32x4 acc[2][2];
        #pragma unroll
        for (int mt = 0; mt < 2; ++mt)
            #pragma unroll
            for (int nt = 0; nt < 2; ++nt)
                acc[mt][nt] = (f32x4){0.f, 0.f, 0.f, 0.f};

        #pragma unroll
        for (int kk = 0; kk < 4; ++kk) {
            bf16x8 bfr[2];
            #pragma unroll
            for (int nt = 0; nt < 2; ++nt) {
                const int row = nt * 16 + fr;
                const int g = (kk * 4 + fq) ^ (row & 7);
                bfr[nt] = *(const bf16x8*)(&Bbuf[cur][row * KHALF + g * 8]);
            }
            #pragma unroll
            for (int mt = 0; mt < 2; ++mt)
                #pragma unroll
                for (int nt = 0; nt < 2; ++nt)
                    acc[mt][nt] = __builtin_amdgcn_mfma_f32_16x16x32_bf16(
                        afm[mt][kk], bfr[nt], acc[mt][nt], 0, 0, 0);
        }

        // ---- epilogue: combine equal tile-diagonals, bijective scatter ----
        {
            f32x4 c0 = acc[0][1];                    // dd = 0  (mt - nt = -1)
            f32x4 c1 = acc[0][0] + acc[1][1];        // dd = 1
            f32x4 c2 = acc[1][0];                    // dd = 2
            const int mub = 4 * fq;
            #pragma unroll
            for (int r = 0; r < 4; ++r) {
                const int mu = mub + r;
                const int dr = mu - fr + 15;         // 0..30
                scratch[wave][mu][dr]      = c0[r];
                scratch[wave][mu][dr + 16] = c1[r];
                scratch[wave][mu][dr + 32] = c2[r];
            }
        }

        // ---- per-wave row-sum: lane owns diagonal delta_rel = lane ----
        {
            float s = 0.f;
            #pragma unroll
            for (int m = 0; m < 16; ++m) s += scratch[wave][m][lane];
            diag[chunk & 1][wave][lane] = s;
        }

        if (chunk + 1 < NCHUNKS) writeB(cur ^ 1);
        __syncthreads();

        // ---- ownership fold: t = 32w + delta_rel, j unique per t -> no atomics ----
        if (tid < 159) {
            float s = 0.f;
            #pragma unroll
            for (int w = 0; w < 4; ++w) {
                const int dr = tid - 32 * w;
                if (dr >= 0 && dr < 63) s += diag[chunk & 1][w][dr];
            }
            int v = m0 - 32 * chunk + tid + 1319;    // in [423, 2373]
            if (v >= 1800) v -= 900;
            if (v >= 900) v -= 900;
            partial[v] += s;
        }
        cur ^= 1;
    }

    __syncthreads();
    for (int i = tid; i < WW; i += 256)
        unsafeAtomicAdd(&out[(size_t)b * WW + i], partial[i]);  // 16 blocks per batch
}

extern "C" void kernel_launch(void* const* d_in, const int* in_sizes, int n_in,
                              void* d_out, int out_size, void* d_ws, size_t ws_size,
                              hipStream_t stream) {
    const float* x1 = (const float*)d_in[0];
    const float* x2 = (const float*)d_in[1];
    float* out = (float*)d_out;
    float* ws = (float*)d_ws;

    const size_t need15 = (size_t)(INV15_OFF + 16384) * sizeof(float);  // ~1.05 MB
    if (ws_size >= need15) {
        const int segs = 15, rowsper = 60;
        nc_norm_partial<<<2 * 32 * segs, 256, 0, stream>>>(x1, x2, ws, out, out_size, segs, rowsper);
        nc_norm_finalize<15><<<64, 256, 0, stream>>>(ws, ws + INV15_OFF);
        nc_corr<<<512, 256, 0, stream>>>(x1, x2, ws + INV15_OFF, out);
    } else {
        const int segs = 4, rowsper = 225;
        nc_norm_partial<<<2 * 32 * segs, 256, 0, stream>>>(x1, x2, ws, out, out_size, segs, rowsper);
        nc_norm_finalize<4><<<64, 256, 0, stream>>>(ws, ws + INV4_OFF);
        nc_corr<<<512, 256, 0, stream>>>(x1, x2, ws + INV4_OFF, out);
    }
}

// Round 13
// 50.591 us; speedup vs baseline: 1.5421x; 1.0910x over previous
//
#include <hip/hip_runtime.h>
#include <hip/hip_bf16.h>

#define BATCH 32
#define WW 900
#define CCH 256
#define PVAL 450
#define KHALF 128     // K columns per block (K-split x2)
#define MSTRIP 128    // M rows per block
#define NCHUNK 64     // B rows staged per chunk (doubled: halves epilogue+barrier count)
#define NCHUNKS 15    // 15*64 = 960 >= 900

typedef __bf16 bf16x8 __attribute__((ext_vector_type(8)));
typedef __bf16 bf16x4 __attribute__((ext_vector_type(4)));
typedef float f32x4 __attribute__((ext_vector_type(4)));

// ws layout (floats): sums [0, 64*segs*256); inv [INV15_OFF or INV4_OFF, +16384)
#define INV15_OFF 245760
#define INV4_OFF  65536

// ---------------- norm pass 1: partial sums of squares (+ fused out-zeroing) ----------------
__global__ void nc_norm_partial(const float* __restrict__ x1,
                                const float* __restrict__ x2,
                                float* __restrict__ sums,
                                float* __restrict__ out, int out_n,
                                int segs, int rowsper) {
    int blk = blockIdx.x;
    int oz = blk * 256 + threadIdx.x;
    if (oz < out_n) out[oz] = 0.f;
    int seg = blk % segs;
    int b = (blk / segs) & 31;
    int which = blk / (segs * 32);
    const float* x = which ? x2 : x1;
    int c = threadIdx.x;
    int r0 = seg * rowsper;
    int r1 = r0 + rowsper;
    if (r1 > WW) r1 = WW;
    const float* p = x + ((size_t)b * WW + r0) * CCH + c;
    float s = 0.f;
    #pragma unroll 4
    for (int w = 0; w < r1 - r0; ++w) {
        float v = p[(size_t)w * CCH];
        s = fmaf(v, v, s);
    }
    sums[(((size_t)(which * 32 + b)) * segs + seg) * CCH + c] = s;
}

// ---------------- norm pass 2: inv = rsqrt(max(sum, eps)) ----------------
template <int SEGS>
__global__ void nc_norm_finalize(float* __restrict__ ws, float* __restrict__ inv) {
    int i = blockIdx.x * 256 + threadIdx.x;
    int c = i & 255;
    int wb = i >> 8;
    const float* s = ws + (size_t)wb * SEGS * CCH + c;
    float t = 0.f;
    #pragma unroll
    for (int q = 0; q < SEGS; ++q) t += s[(size_t)q * CCH];
    inv[i] = rsqrtf(fmaxf(t, 1e-12f));
}

// ---------------- main: GEMM + atomic-free diagonal reduction, 64-row chunks ----------------
// R12 body with NCHUNK=64: acc[2][4], 5 diagonal groups (dd=-3..1, 95 diagonals/chunk),
// epilogue+barrier per 64 rows instead of per 32. Scratch reuses the dead Abuf region
// (A is register-resident after the hoist; barrier separates last read from first write).
__global__ __launch_bounds__(256, 2)
void nc_corr(const float* __restrict__ x1,
             const float* __restrict__ x2,
             const float* __restrict__ invp,
             float* __restrict__ out) {
    __shared__ __bf16 Abuf[MSTRIP * KHALF];       // 32 KB; becomes scratch[4][16][97] after hoist
    __shared__ __bf16 Bbuf[2][NCHUNK * KHALF];    // 2 x 16 KB
    __shared__ float diag[2][4][96];              // 3 KB
    __shared__ float partial[WW];                 // 3.6 KB

    float (*scratch)[16][97] = (float (*)[16][97])Abuf;   // 24.8 KB inside Abuf's 32 KB

    const int tid = threadIdx.x;
    const int b = blockIdx.x & 31;
    const int strip = (blockIdx.x >> 5) & 7;
    const int kh = blockIdx.x >> 8;
    const int m0 = strip * MSTRIP;
    const int k0 = kh * KHALF;

    const float* __restrict__ inv1 = invp + b * CCH + k0;
    const float* __restrict__ inv2 = invp + (BATCH + b) * CCH + k0;
    const float* __restrict__ x1b = x1 + (size_t)b * WW * CCH + k0;
    const float* __restrict__ x2b = x2 + (size_t)b * WW * CCH + k0;

    const int lane = tid & 63;
    const int wave = tid >> 6;     // m-slice: rows m0 + wave*32 .. +31
    const int fr = lane & 15;
    const int fq = lane >> 4;

    // coalesced staging coords
    const int sr = tid >> 5;       // 0..7
    const int sg = tid & 31;       // 0..31

    // ---- B staging: coalesced, 8 float4 per thread per 64-row chunk ----
    const float4 ivB = *(const float4*)(inv2 + sg * 4);
    float4 st[8];

    auto loadB = [&](int chunk) {
        #pragma unroll
        for (int k = 0; k < 8; ++k) {
            const int row = chunk * NCHUNK + sr + 8 * k;
            st[k] = (row < WW) ? *(const float4*)(x2b + (size_t)row * CCH + sg * 4)
                               : make_float4(0.f, 0.f, 0.f, 0.f);
        }
    };
    auto writeB = [&](int buf) {
        #pragma unroll
        for (int k = 0; k < 8; ++k) {
            const int row = sr + 8 * k;        // 0..63
            float4 f = st[k];
            bf16x4 v = { (__bf16)(f.x * ivB.x), (__bf16)(f.y * ivB.y),
                         (__bf16)(f.z * ivB.z), (__bf16)(f.w * ivB.w) };
            *(bf16x4*)(&Bbuf[buf][row * KHALF + (((sg >> 1) ^ sr) << 3) + (sg & 1) * 4]) = v;
        }
    };

    loadB(0);

    // ---- Stage A once: 128 rows x 128 cols, coalesced, normalized, swizzled ----
    {
        float4 iv1 = *(const float4*)(inv1 + sg * 4);
        #pragma unroll
        for (int k = 0; k < 16; ++k) {
            const int row = sr + 8 * k;        // 0..127
            const int m = m0 + row;
            float4 f = make_float4(0.f, 0.f, 0.f, 0.f);
            if (m < WW) f = *(const float4*)(x1b + (size_t)m * CCH + sg * 4);
            bf16x4 v = { (__bf16)(f.x * iv1.x), (__bf16)(f.y * iv1.y),
                         (__bf16)(f.z * iv1.z), (__bf16)(f.w * iv1.w) };
            *(bf16x4*)(&Abuf[row * KHALF + (((sg >> 1) ^ (row & 7)) << 3) + (sg & 1) * 4]) = v;
        }
    }

    for (int i = tid; i < WW; i += 256) partial[i] = 0.f;
    writeB(0);
    __syncthreads();   // A staged, B chunk0 staged, partial zeroed

    // ---- A fragments: LDS -> registers ONCE, pinned against re-sink ----
    bf16x8 afm[2][4];
    #pragma unroll
    for (int mt = 0; mt < 2; ++mt)
        #pragma unroll
        for (int kk = 0; kk < 4; ++kk) {
            const int row = wave * 32 + mt * 16 + fr;
            const int g = (kk * 4 + fq) ^ (row & 7);
            afm[mt][kk] = *(const bf16x8*)(&Abuf[row * KHALF + g * 8]);
        }
    #pragma unroll
    for (int mt = 0; mt < 2; ++mt)
        #pragma unroll
        for (int kk = 0; kk < 4; ++kk)
            asm volatile("" : "+v"(afm[mt][kk]));

    __syncthreads();   // ALL waves done reading Abuf -> safe to reuse as scratch

    // wave-local zero of this wave's scratch region (read only by this wave)
    {
        float* sw = (float*)&scratch[wave][0][0];
        for (int i = lane; i < 16 * 97; i += 64) sw[i] = 0.f;
    }

    int cur = 0;
    for (int chunk = 0; chunk < NCHUNKS; ++chunk) {
        if (chunk + 1 < NCHUNKS) {
            loadB(chunk + 1);                        // issue early (T14)
            __builtin_amdgcn_sched_barrier(0);       // lock prefetch position (anti-sink)
        }

        f32x4 acc[2][4];
        #pragma unroll
        for (int mt = 0; mt < 2; ++mt)
            #pragma unroll
            for (int nt = 0; nt < 4; ++nt)
                acc[mt][nt] = (f32x4){0.f, 0.f, 0.f, 0.f};

        #pragma unroll
        for (int kk = 0; kk < 4; ++kk) {
            bf16x8 bfr[4];
            #pragma unroll
            for (int nt = 0; nt < 4; ++nt) {
                const int row = nt * 16 + fr;
                const int g = (kk * 4 + fq) ^ (row & 7);
                bfr[nt] = *(const bf16x8*)(&Bbuf[cur][row * KHALF + g * 8]);
            }
            #pragma unroll
            for (int mt = 0; mt < 2; ++mt)
                #pragma unroll
                for (int nt = 0; nt < 4; ++nt)
                    acc[mt][nt] = __builtin_amdgcn_mfma_f32_16x16x32_bf16(
                        afm[mt][kk], bfr[nt], acc[mt][nt], 0, 0, 0);
        }

        // ---- epilogue: combine equal tile-diagonals (dd = mt-nt in [-3,1], ddn = dd+3) ----
        // slot: dr = 16*ddn + (mu - fr + 15) in [0,94]; (mu,dr) unique per lane*ddn (verified)
        {
            f32x4 c0 = acc[0][3];                        // ddn = 0
            f32x4 c1 = acc[0][2] + acc[1][3];            // ddn = 1
            f32x4 c2 = acc[0][1] + acc[1][2];            // ddn = 2
            f32x4 c3 = acc[0][0] + acc[1][1];            // ddn = 3
            f32x4 c4 = acc[1][0];                        // ddn = 4
            const int mub = 4 * fq;
            #pragma unroll
            for (int r = 0; r < 4; ++r) {
                const int mu = mub + r;
                const int drb = mu - fr + 15;            // 0..30
                scratch[wave][mu][drb]      = c0[r];
                scratch[wave][mu][drb + 16] = c1[r];
                scratch[wave][mu][drb + 32] = c2[r];
                scratch[wave][mu][drb + 48] = c3[r];
                scratch[wave][mu][drb + 64] = c4[r];
            }
        }

        // ---- per-wave row-sum over mu: lane owns diagonals dr = lane and dr = 64+lane ----
        {
            float s = 0.f;
            #pragma unroll
            for (int m = 0; m < 16; ++m) s += scratch[wave][m][lane];
            diag[chunk & 1][wave][lane] = s;
            if (lane < 31) {
                float s2 = 0.f;
                #pragma unroll
                for (int m = 0; m < 16; ++m) s2 += scratch[wave][m][64 + lane];
                diag[chunk & 1][wave][64 + lane] = s2;
            }
        }

        if (chunk + 1 < NCHUNKS) writeB(cur ^ 1);
        __syncthreads();

        // ---- ownership fold: t = 32w + dr, j unique per t -> plain LDS RMW ----
        if (tid < 191) {
            float s = 0.f;
            #pragma unroll
            for (int w = 0; w < 4; ++w) {
                const int dr = tid - 32 * w;
                if (dr >= 0 && dr < 95) s += diag[chunk & 1][w][dr];
            }
            // j = m0 + t - 64*chunk - 513; +1800 -> [391, 2373]; two conditional subtracts
            int v = m0 - 64 * chunk + tid + 1287;
            if (v >= 1800) v -= 900;
            if (v >= 900) v -= 900;
            partial[v] += s;
        }
        cur ^= 1;
    }

    __syncthreads();
    for (int i = tid; i < WW; i += 256)
        unsafeAtomicAdd(&out[(size_t)b * WW + i], partial[i]);  // 16 blocks per batch
}

extern "C" void kernel_launch(void* const* d_in, const int* in_sizes, int n_in,
                              void* d_out, int out_size, void* d_ws, size_t ws_size,
                              hipStream_t stream) {
    const float* x1 = (const float*)d_in[0];
    const float* x2 = (const float*)d_in[1];
    float* out = (float*)d_out;
    float* ws = (float*)d_ws;

    const size_t need15 = (size_t)(INV15_OFF + 16384) * sizeof(float);  // ~1.05 MB
    if (ws_size >= need15) {
        const int segs = 15, rowsper = 60;
        nc_norm_partial<<<2 * 32 * segs, 256, 0, stream>>>(x1, x2, ws, out, out_size, segs, rowsper);
        nc_norm_finalize<15><<<64, 256, 0, stream>>>(ws, ws + INV15_OFF);
        nc_corr<<<512, 256, 0, stream>>>(x1, x2, ws + INV15_OFF, out);
    } else {
        const int segs = 4, rowsper = 225;
        nc_norm_partial<<<2 * 32 * segs, 256, 0, stream>>>(x1, x2, ws, out, out_size, segs, rowsper);
        nc_norm_finalize<4><<<64, 256, 0, stream>>>(ws, ws + INV4_OFF);
        nc_corr<<<512, 256, 0, stream>>>(x1, x2, ws + INV4_OFF, out);
    }
}

// Round 14
// 50.249 us; speedup vs baseline: 1.5526x; 1.0068x over previous
//
#include <hip/hip_runtime.h>
#include <hip/hip_bf16.h>

#define BATCH 32
#define WW 900
#define CCH 256
#define PVAL 450
#define KHALF 128     // K columns per block (K-split x2)
#define MSTRIP 128    // M rows per block
#define NCHUNK 64     // B rows staged per chunk
#define NCHUNKS 15    // 15*64 = 960 >= 900

typedef __bf16 bf16x8 __attribute__((ext_vector_type(8)));
typedef __bf16 bf16x4 __attribute__((ext_vector_type(4)));
typedef float f32x4 __attribute__((ext_vector_type(4)));

// ws layout (floats): sums [0, 64*segs*256); inv [INV15_OFF or INV4_OFF, +16384)
#define INV15_OFF 245760
#define INV4_OFF  65536

// ---------------- norm pass 1: partial sums of squares (+ fused out-zeroing) ----------------
__global__ void nc_norm_partial(const float* __restrict__ x1,
                                const float* __restrict__ x2,
                                float* __restrict__ sums,
                                float* __restrict__ out, int out_n,
                                int segs, int rowsper) {
    int blk = blockIdx.x;
    int oz = blk * 256 + threadIdx.x;
    if (oz < out_n) out[oz] = 0.f;
    int seg = blk % segs;
    int b = (blk / segs) & 31;
    int which = blk / (segs * 32);
    const float* x = which ? x2 : x1;
    int c = threadIdx.x;
    int r0 = seg * rowsper;
    int r1 = r0 + rowsper;
    if (r1 > WW) r1 = WW;
    const float* p = x + ((size_t)b * WW + r0) * CCH + c;
    float s = 0.f;
    #pragma unroll 4
    for (int w = 0; w < r1 - r0; ++w) {
        float v = p[(size_t)w * CCH];
        s = fmaf(v, v, s);
    }
    sums[(((size_t)(which * 32 + b)) * segs + seg) * CCH + c] = s;
}

// ---------------- norm pass 2: inv = rsqrt(max(sum, eps)) ----------------
template <int SEGS>
__global__ void nc_norm_finalize(float* __restrict__ ws, float* __restrict__ inv) {
    int i = blockIdx.x * 256 + threadIdx.x;
    int c = i & 255;
    int wb = i >> 8;
    const float* s = ws + (size_t)wb * SEGS * CCH + c;
    float t = 0.f;
    #pragma unroll
    for (int q = 0; q < SEGS; ++q) t += s[(size_t)q * CCH];
    inv[i] = rsqrtf(fmaxf(t, 1e-12f));
}

// ---------------- main: GEMM + atomic-free diagonal reduction, 64-row chunks ----------------
// R13 body with ONE change: rowsum's two column reads are unconditional+interleaved so
// the compiler merges each pair into ds_read2_b32 (offsets 64 dwords apart); only the
// diag write keeps the lane<31 guard. (Reads beyond col 97 stay inside Abuf's 32 KB.)
__global__ __launch_bounds__(256, 2)
void nc_corr(const float* __restrict__ x1,
             const float* __restrict__ x2,
             const float* __restrict__ invp,
             float* __restrict__ out) {
    __shared__ __bf16 Abuf[MSTRIP * KHALF];       // 32 KB; becomes scratch[4][16][97] after hoist
    __shared__ __bf16 Bbuf[2][NCHUNK * KHALF];    // 2 x 16 KB
    __shared__ float diag[2][4][96];              // 3 KB
    __shared__ float partial[WW];                 // 3.6 KB

    float (*scratch)[16][97] = (float (*)[16][97])Abuf;   // 24.8 KB inside Abuf's 32 KB

    const int tid = threadIdx.x;
    const int b = blockIdx.x & 31;
    const int strip = (blockIdx.x >> 5) & 7;
    const int kh = blockIdx.x >> 8;
    const int m0 = strip * MSTRIP;
    const int k0 = kh * KHALF;

    const float* __restrict__ inv1 = invp + b * CCH + k0;
    const float* __restrict__ inv2 = invp + (BATCH + b) * CCH + k0;
    const float* __restrict__ x1b = x1 + (size_t)b * WW * CCH + k0;
    const float* __restrict__ x2b = x2 + (size_t)b * WW * CCH + k0;

    const int lane = tid & 63;
    const int wave = tid >> 6;     // m-slice: rows m0 + wave*32 .. +31
    const int fr = lane & 15;
    const int fq = lane >> 4;

    // coalesced staging coords
    const int sr = tid >> 5;       // 0..7
    const int sg = tid & 31;       // 0..31

    // ---- B staging: coalesced, 8 float4 per thread per 64-row chunk ----
    const float4 ivB = *(const float4*)(inv2 + sg * 4);
    float4 st[8];

    auto loadB = [&](int chunk) {
        #pragma unroll
        for (int k = 0; k < 8; ++k) {
            const int row = chunk * NCHUNK + sr + 8 * k;
            st[k] = (row < WW) ? *(const float4*)(x2b + (size_t)row * CCH + sg * 4)
                               : make_float4(0.f, 0.f, 0.f, 0.f);
        }
    };
    auto writeB = [&](int buf) {
        #pragma unroll
        for (int k = 0; k < 8; ++k) {
            const int row = sr + 8 * k;        // 0..63
            float4 f = st[k];
            bf16x4 v = { (__bf16)(f.x * ivB.x), (__bf16)(f.y * ivB.y),
                         (__bf16)(f.z * ivB.z), (__bf16)(f.w * ivB.w) };
            *(bf16x4*)(&Bbuf[buf][row * KHALF + (((sg >> 1) ^ sr) << 3) + (sg & 1) * 4]) = v;
        }
    };

    loadB(0);

    // ---- Stage A once: 128 rows x 128 cols, coalesced, normalized, swizzled ----
    {
        float4 iv1 = *(const float4*)(inv1 + sg * 4);
        #pragma unroll
        for (int k = 0; k < 16; ++k) {
            const int row = sr + 8 * k;        // 0..127
            const int m = m0 + row;
            float4 f = make_float4(0.f, 0.f, 0.f, 0.f);
            if (m < WW) f = *(const float4*)(x1b + (size_t)m * CCH + sg * 4);
            bf16x4 v = { (__bf16)(f.x * iv1.x), (__bf16)(f.y * iv1.y),
                         (__bf16)(f.z * iv1.z), (__bf16)(f.w * iv1.w) };
            *(bf16x4*)(&Abuf[row * KHALF + (((sg >> 1) ^ (row & 7)) << 3) + (sg & 1) * 4]) = v;
        }
    }

    for (int i = tid; i < WW; i += 256) partial[i] = 0.f;
    writeB(0);
    __syncthreads();   // A staged, B chunk0 staged, partial zeroed

    // ---- A fragments: LDS -> registers ONCE, pinned against re-sink ----
    bf16x8 afm[2][4];
    #pragma unroll
    for (int mt = 0; mt < 2; ++mt)
        #pragma unroll
        for (int kk = 0; kk < 4; ++kk) {
            const int row = wave * 32 + mt * 16 + fr;
            const int g = (kk * 4 + fq) ^ (row & 7);
            afm[mt][kk] = *(const bf16x8*)(&Abuf[row * KHALF + g * 8]);
        }
    #pragma unroll
    for (int mt = 0; mt < 2; ++mt)
        #pragma unroll
        for (int kk = 0; kk < 4; ++kk)
            asm volatile("" : "+v"(afm[mt][kk]));

    __syncthreads();   // ALL waves done reading Abuf -> safe to reuse as scratch

    // wave-local zero of this wave's scratch region (read only by this wave)
    {
        float* sw = (float*)&scratch[wave][0][0];
        for (int i = lane; i < 16 * 97; i += 64) sw[i] = 0.f;
    }

    int cur = 0;
    for (int chunk = 0; chunk < NCHUNKS; ++chunk) {
        if (chunk + 1 < NCHUNKS) {
            loadB(chunk + 1);                        // issue early (T14)
            __builtin_amdgcn_sched_barrier(0);       // lock prefetch position (anti-sink)
        }

        f32x4 acc[2][4];
        #pragma unroll
        for (int mt = 0; mt < 2; ++mt)
            #pragma unroll
            for (int nt = 0; nt < 4; ++nt)
                acc[mt][nt] = (f32x4){0.f, 0.f, 0.f, 0.f};

        #pragma unroll
        for (int kk = 0; kk < 4; ++kk) {
            bf16x8 bfr[4];
            #pragma unroll
            for (int nt = 0; nt < 4; ++nt) {
                const int row = nt * 16 + fr;
                const int g = (kk * 4 + fq) ^ (row & 7);
                bfr[nt] = *(const bf16x8*)(&Bbuf[cur][row * KHALF + g * 8]);
            }
            #pragma unroll
            for (int mt = 0; mt < 2; ++mt)
                #pragma unroll
                for (int nt = 0; nt < 4; ++nt)
                    acc[mt][nt] = __builtin_amdgcn_mfma_f32_16x16x32_bf16(
                        afm[mt][kk], bfr[nt], acc[mt][nt], 0, 0, 0);
        }

        // ---- epilogue: combine equal tile-diagonals (dd = mt-nt in [-3,1], ddn = dd+3) ----
        {
            f32x4 c0 = acc[0][3];                        // ddn = 0
            f32x4 c1 = acc[0][2] + acc[1][3];            // ddn = 1
            f32x4 c2 = acc[0][1] + acc[1][2];            // ddn = 2
            f32x4 c3 = acc[0][0] + acc[1][1];            // ddn = 3
            f32x4 c4 = acc[1][0];                        // ddn = 4
            const int mub = 4 * fq;
            #pragma unroll
            for (int r = 0; r < 4; ++r) {
                const int mu = mub + r;
                const int drb = mu - fr + 15;            // 0..30
                scratch[wave][mu][drb]      = c0[r];
                scratch[wave][mu][drb + 16] = c1[r];
                scratch[wave][mu][drb + 32] = c2[r];
                scratch[wave][mu][drb + 48] = c3[r];
                scratch[wave][mu][drb + 64] = c4[r];
            }
        }

        // ---- per-wave row-sum: unconditional paired reads -> ds_read2_b32 merge ----
        // (reads at col 64+lane may exceed 97 but stay inside Abuf's 32 KB; garbage
        //  lands in s2 which is discarded for lane >= 31 at the guarded write below)
        {
            float s = 0.f, s2 = 0.f;
            #pragma unroll
            for (int m = 0; m < 16; ++m) {
                s  += scratch[wave][m][lane];
                s2 += scratch[wave][m][64 + lane];
            }
            diag[chunk & 1][wave][lane] = s;
            if (lane < 31) diag[chunk & 1][wave][64 + lane] = s2;
        }

        if (chunk + 1 < NCHUNKS) writeB(cur ^ 1);
        __syncthreads();

        // ---- ownership fold: t = 32w + dr, j unique per t -> plain LDS RMW ----
        if (tid < 191) {
            float s = 0.f;
            #pragma unroll
            for (int w = 0; w < 4; ++w) {
                const int dr = tid - 32 * w;
                if (dr >= 0 && dr < 95) s += diag[chunk & 1][w][dr];
            }
            int v = m0 - 64 * chunk + tid + 1287;
            if (v >= 1800) v -= 900;
            if (v >= 900) v -= 900;
            partial[v] += s;
        }
        cur ^= 1;
    }

    __syncthreads();
    for (int i = tid; i < WW; i += 256)
        unsafeAtomicAdd(&out[(size_t)b * WW + i], partial[i]);  // 16 blocks per batch
}

extern "C" void kernel_launch(void* const* d_in, const int* in_sizes, int n_in,
                              void* d_out, int out_size, void* d_ws, size_t ws_size,
                              hipStream_t stream) {
    const float* x1 = (const float*)d_in[0];
    const float* x2 = (const float*)d_in[1];
    float* out = (float*)d_out;
    float* ws = (float*)d_ws;

    const size_t need15 = (size_t)(INV15_OFF + 16384) * sizeof(float);  // ~1.05 MB
    if (ws_size >= need15) {
        const int segs = 15, rowsper = 60;
        nc_norm_partial<<<2 * 32 * segs, 256, 0, stream>>>(x1, x2, ws, out, out_size, segs, rowsper);
        nc_norm_finalize<15><<<64, 256, 0, stream>>>(ws, ws + INV15_OFF);
        nc_corr<<<512, 256, 0, stream>>>(x1, x2, ws + INV15_OFF, out);
    } else {
        const int segs = 4, rowsper = 225;
        nc_norm_partial<<<2 * 32 * segs, 256, 0, stream>>>(x1, x2, ws, out, out_size, segs, rowsper);
        nc_norm_finalize<4><<<64, 256, 0, stream>>>(ws, ws + INV4_OFF);
        nc_corr<<<512, 256, 0, stream>>>(x1, x2, ws + INV4_OFF, out);
    }
}